// Round 6
// baseline (370.296 us; speedup 1.0000x reference)
//
#include <hip/hip_runtime.h>
#include <math.h>

// Problem constants (fixed by the reference)
constexpr int Bb  = 2;
constexpr int Ss  = 2048;
constexpr int Dd  = 2048;
constexpr int Hh  = 16;
constexpr int DHd = 128;
constexpr int BS  = Bb * Ss;   // 4096
constexpr int NQKV = 2304;     // 2048 q + 128 k + 128 v

typedef __bf16 bf16x8 __attribute__((ext_vector_type(8)));
typedef float  f32x4  __attribute__((ext_vector_type(4)));

// fp32 -> bf16 (RNE), bit-level
static __device__ __forceinline__ unsigned short f2bf(float f) {
  union { float f; unsigned int u; } a; a.f = f;
  unsigned int u = a.u;
  unsigned int r = (u + 0x7fffu + ((u >> 16) & 1u)) >> 16;
  return (unsigned short)r;
}
static __device__ __forceinline__ float bf2f(unsigned short u) {
  union { unsigned int u; float f; } a; a.u = ((unsigned int)u) << 16;
  return a.f;
}
// pack two fp32 -> one dword of 2 bf16 (lo = first)
static __device__ __forceinline__ int pk2bf(float lo, float hi) {
  return (int)((unsigned int)f2bf(lo) | ((unsigned int)f2bf(hi) << 16));
}
static __device__ __forceinline__ f32x4 mfma16(bf16x8 a, bf16x8 b, f32x4 c) {
  return __builtin_amdgcn_mfma_f32_16x16x32_bf16(a, b, c, 0, 0, 0);
}

// ---------------------------------------------------------------------------
// cast ALL fp32 inputs -> bf16 into one contiguous ws region:
//   [qw (2048x2048) | kvw (256x2048) | ow (2048x2048) | x (4096x2048)]
// ---------------------------------------------------------------------------
__global__ __launch_bounds__(256) void cast_all(
    const float* __restrict__ qw, const float* __restrict__ kvw,
    const float* __restrict__ ow, const float* __restrict__ x,
    unsigned short* __restrict__ dst)
{
  const int i = blockIdx.x * 256 + threadIdx.x;   // grid sized exactly
  const float* src; int off;
  if (i < 1048576)      { src = qw;  off = 0; }
  else if (i < 1179648) { src = kvw; off = 1048576; }
  else if (i < 2228224) { src = ow;  off = 1179648; }
  else                  { src = x;   off = 2228224; }
  const float4 v = ((const float4*)src)[i - off];
  ushort4 o;
  o.x = f2bf(v.x); o.y = f2bf(v.y); o.z = f2bf(v.z); o.w = f2bf(v.w);
  ((ushort4*)dst)[i] = o;
}

// ---------------------------------------------------------------------------
// bf16 MFMA GEMM: C[M][N] = A[M][K] @ Bw[N][K]^T + bias(col).
// bias(col) = col < nsplit ? bias1[col] : bias2[col-nsplit]  (merged QKV).
// 128x128 tile, BK=32, 256 threads, global_load_lds width-16 staging.
// ---------------------------------------------------------------------------
#define TM 128
#define TN 128
#define TK 32

#define GLOAD16(gp, lp)                                                        \
  __builtin_amdgcn_global_load_lds(                                            \
      (const __attribute__((address_space(1))) void*)(gp),                     \
      (__attribute__((address_space(3))) void*)(lp), 16, 0, 0)

template <bool BF16OUT>
__global__ __launch_bounds__(256) void gemm_bt_mfma(
    const unsigned short* __restrict__ A,    // M x K bf16
    const unsigned short* __restrict__ Bw,   // N x K bf16
    const float* __restrict__ bias1,
    const float* __restrict__ bias2,
    int nsplit,
    void* __restrict__ Cv,                   // M x N (fp32 or bf16)
    int M, int N, int K)
{
  __shared__ unsigned short As[TM * TK];   // 8 KB
  __shared__ unsigned short Bs[TN * TK];   // 8 KB

  const int tid  = threadIdx.x;
  const int w    = tid >> 6;
  const int lane = tid & 63;
  const int m0   = blockIdx.y * TM;
  const int n0   = blockIdx.x * TN;
  const int wm   = (w >> 1) * 64;
  const int wn   = (w & 1) * 64;

  f32x4 acc[4][4];
#pragma unroll
  for (int i = 0; i < 4; i++)
#pragma unroll
    for (int j = 0; j < 4; j++) acc[i][j] = (f32x4){0.f, 0.f, 0.f, 0.f};

  const int srow = lane >> 2;
  const int scol = (lane & 3) * 8;
  const unsigned short* aG0 = A  + (size_t)(m0 +      w * 16 + srow) * K + scol;
  const unsigned short* aG1 = A  + (size_t)(m0 + 64 + w * 16 + srow) * K + scol;
  const unsigned short* bG0 = Bw + (size_t)(n0 +      w * 16 + srow) * K + scol;
  const unsigned short* bG1 = Bw + (size_t)(n0 + 64 + w * 16 + srow) * K + scol;
  unsigned short* aL0 = &As[(     w * 16) * TK];
  unsigned short* aL1 = &As[(64 + w * 16) * TK];
  unsigned short* bL0 = &Bs[(     w * 16) * TK];
  unsigned short* bL1 = &Bs[(64 + w * 16) * TK];

  const int fr = lane & 15;
  const int fk = (lane >> 4) * 8;

  for (int k0 = 0; k0 < K; k0 += TK) {
    __syncthreads();
    GLOAD16(aG0 + k0, aL0);
    GLOAD16(aG1 + k0, aL1);
    GLOAD16(bG0 + k0, bL0);
    GLOAD16(bG1 + k0, bL1);
    __syncthreads();

    bf16x8 af[4], bfr[4];
#pragma unroll
    for (int i = 0; i < 4; i++)
      af[i] = *(const bf16x8*)&As[(wm + i * 16 + fr) * TK + fk];
#pragma unroll
    for (int j = 0; j < 4; j++)
      bfr[j] = *(const bf16x8*)&Bs[(wn + j * 16 + fr) * TK + fk];
#pragma unroll
    for (int i = 0; i < 4; i++)
#pragma unroll
      for (int j = 0; j < 4; j++)
        acc[i][j] = mfma16(af[i], bfr[j], acc[i][j]);
  }

  const int er = (lane >> 4) * 4;
  const int ec = lane & 15;
#pragma unroll
  for (int j = 0; j < 4; j++) {
    const int col = n0 + wn + j * 16 + ec;
    const float bv = (col < nsplit) ? bias1[col] : bias2[col - nsplit];
#pragma unroll
    for (int i = 0; i < 4; i++) {
      const int rbase = m0 + wm + i * 16 + er;
#pragma unroll
      for (int r = 0; r < 4; r++) {
        const float v = acc[i][j][r] + bv;
        if constexpr (BF16OUT)
          ((unsigned short*)Cv)[(size_t)(rbase + r) * N + col] = f2bf(v);
        else
          ((float*)Cv)[(size_t)(rbase + r) * N + col] = v;
      }
    }
  }
}

// ---------------------------------------------------------------------------
// RoPE in-place on q columns of QKV bf16 (B,S,2304).
// ---------------------------------------------------------------------------
__global__ __launch_bounds__(256) void rope_q_bf16(unsigned short* __restrict__ QKV)
{
  const int row = blockIdx.x;        // b*S + s
  const int s   = row & (Ss - 1);
  const int t   = threadIdx.x;
  const int h   = t >> 4, p = t & 15;
  unsigned short* base = QKV + (size_t)row * NQKV + h * DHd + p * 4;

  union { ushort4 v; unsigned short a[4]; } lo, hi, olo, ohi;
  lo.v = *(ushort4*)base;
  hi.v = *(ushort4*)(base + 64);
#pragma unroll
  for (int d = 0; d < 4; d++) {
    const int i = p * 4 + d;
    const float invf = exp2f(-(float)i * (13.287712379549449f / 64.0f)); // 10000^(-i/64)
    const float ang = (float)s * invf;
    const float c = cosf(ang), sn = sinf(ang);
    const float l = bf2f(lo.a[d]), hh = bf2f(hi.a[d]);
    olo.a[d] = f2bf(l * c - hh * sn);
    ohi.a[d] = f2bf(hh * c + l * sn);
  }
  *(ushort4*)base        = olo.v;
  *(ushort4*)(base + 64) = ohi.v;
}

// ---------------------------------------------------------------------------
// prep_kv: from QKV bf16 (B,S,2304) — k cols [2048,2176), v cols [2176,2304) —
// produce Kb (B,S,128) roped and Vt (B,128,S) transposed.
// ---------------------------------------------------------------------------
__global__ __launch_bounds__(256) void prep_kv(
    const unsigned short* __restrict__ QKV,
    unsigned short* __restrict__ Kb,
    unsigned short* __restrict__ Vt)
{
  __shared__ unsigned short Vtile[64 * 136];   // [s_local][d], padded

  const int blk = blockIdx.x;          // b*32 + stile
  const int b   = blk >> 5;
  const int s0  = (blk & 31) * 64;
  const int t   = threadIdx.x;

  // --- rope K
  {
    const int r = t >> 2, p = t & 3;
    const int row = blk * 64 + r;
    const int s = row & (Ss - 1);
    const unsigned short* src = QKV + (size_t)row * NQKV + 2048 + p * 16;
    union { uint4 v[2]; unsigned short a[16]; } lo, hi, ol, oh;
    lo.v[0] = *(const uint4*)src;        lo.v[1] = *(const uint4*)(src + 8);
    hi.v[0] = *(const uint4*)(src + 64); hi.v[1] = *(const uint4*)(src + 72);
#pragma unroll
    for (int e = 0; e < 16; e++) {
      const int i = p * 16 + e;
      const float invf = exp2f(-(float)i * (13.287712379549449f / 64.0f));
      const float ang = (float)s * invf;
      const float c = cosf(ang), sn = sinf(ang);
      const float l = bf2f(lo.a[e]), hh = bf2f(hi.a[e]);
      ol.a[e] = f2bf(l * c - hh * sn);
      oh.a[e] = f2bf(hh * c + l * sn);
    }
    unsigned short* dst = Kb + (size_t)row * 128 + p * 16;
    *(uint4*)dst        = ol.v[0]; *(uint4*)(dst + 8)  = ol.v[1];
    *(uint4*)(dst + 64) = oh.v[0]; *(uint4*)(dst + 72) = oh.v[1];
  }

  // --- stage V into LDS, s-major
#pragma unroll
  for (int c = 0; c < 4; c++) {
    const int id = c * 256 + t;
    const int vr = id >> 4, cc = id & 15;
    *(uint4*)&Vtile[vr * 136 + cc * 8] =
        *(const uint4*)(QKV + (size_t)(blk * 64 + vr) * NQKV + 2176 + cc * 8);
  }
  __syncthreads();

  // --- write Vt rows
  {
    const int d = t >> 1, half = t & 1;
    union { uint4 v[4]; unsigned short a[32]; } val;
#pragma unroll
    for (int kk = 0; kk < 32; kk++)
      val.a[kk] = Vtile[(half * 32 + kk) * 136 + d];
    unsigned short* dst = Vt + ((size_t)(b * 128 + d)) * Ss + s0 + half * 32;
#pragma unroll
    for (int c = 0; c < 4; c++) *(uint4*)(dst + c * 8) = val.v[c];
  }
}

// ---------------------------------------------------------------------------
// flash_v6: causal MQA attention. Grid (S/64, H, B) = 1024 blocks,
// 128 threads = 2 waves; wave w owns q-rows q0+32w..+31 (2 q-tiles of 16).
// LDS (XOR-swizzled, 128B rows):
//   Ks: 2 panels [64 keys][64 dh]  — panel p covers dh p*64..+63 (16 KB)
//   Vs: [128 dh][64 keys]                                        (16 KB)
// Swizzle: 16B chunk g of row r is stored at chunk (g ^ (r&7)); staging
// fetches global chunk ((lane&7) ^ (lane>>3)) so the contiguous
// global_load_lds lane mapping realizes the permutation. Reads XOR with
// (lm&7) -> any 16 consecutive lanes spread 2-per-bank-group (free).
// Max-free softmax (p = exp2(s*scale), masked); P transposed C->B layout
// in-register (shuffles); O^T = V^T · P^T accumulated in C-layout.
// ---------------------------------------------------------------------------
__global__ __launch_bounds__(128) void flash_v6(
    const unsigned short* __restrict__ QKV,  // (B,S,2304), q roped in [0,2048)
    const unsigned short* __restrict__ Kb,   // (B,S,128) roped
    const unsigned short* __restrict__ Vt,   // (B,128,S)
    unsigned short* __restrict__ attn)       // (B,S,2048) bf16
{
  __shared__ unsigned short Ks[2 * 64 * 64];   // 16 KB
  __shared__ unsigned short Vs[128 * 64];      // 16 KB

  const int qt = 31 - (int)blockIdx.x;         // heavy tiles first
  const int h = blockIdx.y, b = blockIdx.z;
  const int q0 = qt * 64;
  const int tid = threadIdx.x;
  const int w = tid >> 6, lane = tid & 63;
  const int lg = lane >> 4, lm = lane & 15;
  const int qrow_hi = q0 + w * 32 + 31;        // wave's last q-row

  // Q as B-operand frags: [n qtile][kf]: lane: n-idx=qrow(lm), k = kf*32+lg*8
  bf16x8 qf[2][4];
#pragma unroll
  for (int n = 0; n < 2; n++) {
    const unsigned short* qp =
        QKV + (size_t)(b * Ss + q0 + w * 32 + n * 16 + lm) * NQKV + h * DHd + lg * 8;
#pragma unroll
    for (int kf = 0; kf < 4; kf++) qf[n][kf] = *(const bf16x8*)(qp + kf * 32);
  }

  // O^T accumulators, C-layout: (dh = dt*16 + 4*lg + r, qrow = lm) per qtile n
  f32x4 ot[2][8];
#pragma unroll
  for (int n = 0; n < 2; n++)
#pragma unroll
    for (int dt = 0; dt < 8; dt++) ot[n][dt] = (f32x4){0.f, 0.f, 0.f, 0.f};
  float lsum[2] = {0.f, 0.f};

  const float sscale = 0.08838834764831845f * 1.4426950408889634f; // /sqrt(128)*log2e

  // staging: lane covers row sr = lane>>3 (of 8 per call), chunk c = lane&7;
  // fetch global chunk (c ^ sr) so LDS chunk c holds global (c ^ sr).
  const int sr  = lane >> 3;
  const int cg8 = ((lane & 7) ^ sr) * 8;       // global element offset of chunk
  const unsigned short* kgp =
      Kb + (size_t)b * Ss * 128 + (size_t)sr * 128 + w * 64 + cg8;
  const unsigned short* vgp =
      Vt + (size_t)b * 128 * Ss + (size_t)(w * 64 + sr) * Ss + cg8;
  unsigned short* ksl = &Ks[w * 4096];         // wave w stages panel p=w
  // read-side swizzle constant
  const int xk8 = (lm & 7) * 8;

  // transpose shuffle sources (C->B layout, within a 32-key half)
  const int addr0 = (2 * (lg & 1)) * 16 + lm;   // dwords 0,1
  const int addr1 = addr0 + 16;                 // dwords 2,3
  const bool sel_hi = (lg & 2) != 0;

  // one 32-key half: key tiles tA0, tA0+1; V key-chunk base vg8 = jj*32
  auto half32 = [&](int kb, int tA0, int vg8) {
    // K frags for the 2 key tiles (shared by both q-tiles)
    f32x4 s[2][2];
#pragma unroll
    for (int n = 0; n < 2; n++) {
      s[n][0] = (f32x4){0.f, 0.f, 0.f, 0.f};
      s[n][1] = (f32x4){0.f, 0.f, 0.f, 0.f};
    }
#pragma unroll
    for (int t = 0; t < 2; t++) {
      const int row = (tA0 + t) * 16 + lm;
#pragma unroll
      for (int kf = 0; kf < 4; kf++) {
        const int p = kf >> 1;
        const int g8 = (kf & 1) * 32 + lg * 8;
        const bf16x8 kf8 = *(const bf16x8*)&Ks[p * 4096 + row * 64 + (g8 ^ xk8)];
        s[0][t] = mfma16(kf8, qf[0][kf], s[0][t]);
        s[1][t] = mfma16(kf8, qf[1][kf], s[1][t]);
      }
    }
    // mask + exp2 (max-free) + pack, per q-tile
#pragma unroll
    for (int n = 0; n < 2; n++) {
      const int qn = q0 + w * 32 + n * 16 + lm;
      int pk[2][2];
#pragma unroll
      for (int t = 0; t < 2; t++) {
        float p[4];
#pragma unroll
        for (int r = 0; r < 4; r++) {
          const int key = kb + t * 16 + 4 * lg + r;
          const float ev = exp2f(s[n][t][r] * sscale);
          p[r] = (key <= qn) ? ev : 0.f;
          lsum[n] += p[r];
        }
        pk[t][0] = pk2bf(p[0], p[1]);
        pk[t][1] = pk2bf(p[2], p[3]);
      }
      // C-layout -> B-layout transpose (shuffles)
      union { int d[4]; bf16x8 v; } pb;
#pragma unroll
      for (int d = 0; d < 4; d++) {
        const int src = (d < 2) ? addr0 : addr1;
        const int v0 = __shfl(pk[0][d & 1], src);
        const int v1 = __shfl(pk[1][d & 1], src);
        pb.d[d] = sel_hi ? v1 : v0;
      }
      // PV: O^T += V^T(32 keys) · P^T
#pragma unroll
      for (int dt = 0; dt < 8; dt++) {
        const bf16x8 vfrag =
            *(const bf16x8*)&Vs[(dt * 16 + lm) * 64 + ((vg8 + lg * 8) ^ xk8)];
        ot[n][dt] = mfma16(vfrag, pb.v, ot[n][dt]);
      }
    }
  };

  for (int j0 = 0; j0 <= q0; j0 += 64) {
    __syncthreads();            // previous iteration's LDS readers done
    // stage K panel w: [64 keys][dh w*64..+63], 8 calls x 8 rows
#pragma unroll
    for (int i = 0; i < 8; i++)
      GLOAD16(kgp + (size_t)(j0 + i * 8) * 128, ksl + i * 512);
    // stage V dh rows w*64..+63, keys j0..j0+63: 8 calls x 8 rows
#pragma unroll
    for (int i = 0; i < 8; i++)
      GLOAD16(vgp + (size_t)(i * 8) * Ss + j0, &Vs[(w * 64 + i * 8) * 64]);
    __syncthreads();            // vmcnt(0) drained before use

    half32(j0, 0, 0);                        // keys j0..j0+31
    if (j0 + 32 <= qrow_hi)                  // wave-uniform skip
      half32(j0 + 32, 2, 32);                // keys j0+32..j0+63
  }

  // reduce lsum over the 4 lg groups (same lm = same qrow)
#pragma unroll
  for (int n = 0; n < 2; n++) {
    lsum[n] += __shfl_xor(lsum[n], 16);
    lsum[n] += __shfl_xor(lsum[n], 32);
  }

  // store: lane covers (qrow = lm of tile n, dh = dt*16 + 4lg + 0..3)
#pragma unroll
  for (int n = 0; n < 2; n++) {
    const float inv = 1.0f / lsum[n];
    unsigned short* dst =
        attn + (size_t)(b * Ss + q0 + w * 32 + n * 16 + lm) * Dd + h * DHd + lg * 4;
#pragma unroll
    for (int dt = 0; dt < 8; dt++) {
      ushort4 o4;
      o4.x = f2bf(ot[n][dt][0] * inv);
      o4.y = f2bf(ot[n][dt][1] * inv);
      o4.z = f2bf(ot[n][dt][2] * inv);
      o4.w = f2bf(ot[n][dt][3] * inv);
      *(ushort4*)(dst + dt * 16) = o4;
    }
  }
}

// ---------------------------------------------------------------------------
extern "C" void kernel_launch(void* const* d_in, const int* in_sizes, int n_in,
                              void* d_out, int out_size, void* d_ws, size_t ws_size,
                              hipStream_t stream) {
  const float* x   = (const float*)d_in[0];   // (B,S,D)
  const float* qw  = (const float*)d_in[1];   // (2048, 2048)
  const float* qb  = (const float*)d_in[2];
  const float* kvw = (const float*)d_in[3];   // (256, 2048)
  const float* kvb = (const float*)d_in[4];
  const float* ow  = (const float*)d_in[5];   // (2048, 2048)
  const float* ob  = (const float*)d_in[6];
  float* out = (float*)d_out;

  // workspace layout (bf16 elements):
  //   wqkv @ 0          (2304 x 2048)   qw rows 0-2047, kvw 2048-2303
  //   owb  @ 4,718,592  (2048 x 2048)
  //   xb   @ 8,912,896  (4096 x 2048)   -> reused as attn_b
  //   QKV  @ 17,301,504 (4096 x 2304)
  //   Kb   @ 26,738,688 (4096 x 128)
  //   Vt   @ 27,262,976 (2 x 128 x 2048)
  unsigned short* wsb    = (unsigned short*)d_ws;
  unsigned short* wqkv   = wsb;
  unsigned short* owb    = wsb + 4718592;
  unsigned short* xb     = wsb + 8912896;
  unsigned short* attn_b = xb;                 // alias: xb dead after QKV gemm
  unsigned short* QKV    = wsb + 17301504;
  unsigned short* Kb     = wsb + 26738688;
  unsigned short* Vt     = wsb + 27262976;

  // 1. all fp32->bf16 casts in one kernel
  cast_all<<<16896, 256, 0, stream>>>(qw, kvw, ow, x, wqkv);

  // 2. merged QKV projection: (4096 x 2304) = xb @ wqkv^T + [qb|kvb]
  gemm_bt_mfma<true><<<dim3(NQKV / TN, BS / TM), 256, 0, stream>>>(
      xb, wqkv, qb, kvb, 2048, QKV, BS, NQKV, Dd);

  // 3. RoPE q in-place; 4. K rope + V transpose
  rope_q_bf16<<<BS, 256, 0, stream>>>(QKV);
  prep_kv<<<BS / 64, 256, 0, stream>>>(QKV, Kb, Vt);

  // 5. flash attention (swizzled LDS, 32 q-rows/wave)
  flash_v6<<<dim3(Ss / 64, Hh, Bb), 128, 0, stream>>>(QKV, Kb, Vt, attn_b);

  // 6. O projection: out = attn @ ow^T + ob (fp32 out)
  gemm_bt_mfma<false><<<dim3(Dd / TN, BS / TM), 256, 0, stream>>>(
      attn_b, owb, ob, ob, Dd, out, BS, Dd, Dd);
}